// Round 1
// baseline (103.274 us; speedup 1.0000x reference)
//
#include <hip/hip_runtime.h>

#define B_ 2
#define A_ 16384
#define C_ 15
#define G_ 16
#define D2Rf 0.017453292519943295f

// ---------------------------------------------------------------------------
// Rotated IoU, replicating the JAX reference op-for-op in fp32.
// ---------------------------------------------------------------------------
__device__ __forceinline__ void rect_corners5(const float* b, float X[4], float Y[4],
                                              float* cth, float* sth) {
    float th = b[4] * D2Rf;
    float c = cosf(th), s = sinf(th);
    *cth = c; *sth = s;
    const float SX[4] = {-1.f, 1.f, 1.f, -1.f};
    const float SY[4] = {-1.f, -1.f, 1.f, 1.f};
    float hw = 0.5f * b[2], hh = 0.5f * b[3];
#pragma unroll
    for (int i = 0; i < 4; ++i) {
        float dx = hw * SX[i];
        float dy = hh * SY[i];
        X[i] = b[0] + dx * c - dy * s;
        Y[i] = b[1] + dx * s + dy * c;
    }
}

__device__ float rotated_iou_pair(const float* ab, const float* gb) {
    float ax[4], ay[4], gx[4], gy[4];
    float cA, sA, cG, sG;
    rect_corners5(ab, ax, ay, &cA, &sA);
    rect_corners5(gb, gx, gy, &cG, &sG);

    float rx[24], ry[24];
    unsigned msk = 0u;

    // corners of A in G  (indices 0..3)
#pragma unroll
    for (int i = 0; i < 4; ++i) {
        float dx = ax[i] - gb[0], dy = ay[i] - gb[1];
        float lx = dx * cG + dy * sG;
        float ly = -dx * sG + dy * cG;
        bool in = (fabsf(lx) <= 0.5f * gb[2] + 1e-4f) && (fabsf(ly) <= 0.5f * gb[3] + 1e-4f);
        rx[i] = ax[i]; ry[i] = ay[i];
        if (in) msk |= (1u << i);
    }
    // corners of G in A  (indices 4..7)
#pragma unroll
    for (int i = 0; i < 4; ++i) {
        float dx = gx[i] - ab[0], dy = gy[i] - ab[1];
        float lx = dx * cA + dy * sA;
        float ly = -dx * sA + dy * cA;
        bool in = (fabsf(lx) <= 0.5f * ab[2] + 1e-4f) && (fabsf(ly) <= 0.5f * ab[3] + 1e-4f);
        rx[4 + i] = gx[i]; ry[4 + i] = gy[i];
        if (in) msk |= (1u << (4 + i));
    }
    // edge intersections (indices 8..23, i-major j-minor)
#pragma unroll
    for (int i = 0; i < 4; ++i) {
        float p0x = ax[i], p0y = ay[i];
        float p1x = ax[(i + 1) & 3], p1y = ay[(i + 1) & 3];
        float d1x = p1x - p0x, d1y = p1y - p0y;
#pragma unroll
        for (int j = 0; j < 4; ++j) {
            float q0x = gx[j], q0y = gy[j];
            float q1x = gx[(j + 1) & 3], q1y = gy[(j + 1) & 3];
            float d2x = q1x - q0x, d2y = q1y - q0y;
            float rrx = q0x - p0x, rry = q0y - p0y;
            float den = d1x * d2y - d1y * d2x;
            float safe = (fabsf(den) < 1e-8f) ? 1.f : den;
            float t = (rrx * d2y - rry * d2x) / safe;
            float u = (rrx * d1y - rry * d1x) / safe;
            bool ok = (fabsf(den) >= 1e-8f) && (t >= 0.f) && (t <= 1.f) && (u >= 0.f) && (u <= 1.f);
            int k = 8 + i * 4 + j;
            rx[k] = p0x + t * d1x;
            ry[k] = p0y + t * d1y;
            if (ok) msk |= (1u << k);
        }
    }

    int cnt = __popc(msk);
    float sx = 0.f, sy = 0.f;
#pragma unroll
    for (int k = 0; k < 24; ++k)
        if ((msk >> k) & 1u) { sx += rx[k]; sy += ry[k]; }
    float cnf = fmaxf((float)cnt, 1.f);
    float cenx = sx / cnf, ceny = sy / cnf;

    float ang[24];
#pragma unroll
    for (int k = 0; k < 24; ++k) {
        if ((msk >> k) & 1u) {
            rx[k] -= cenx; ry[k] -= ceny;
            ang[k] = atan2f(ry[k], rx[k]);
        } else {
            rx[k] = 0.f; ry[k] = 0.f;
            ang[k] = 1e9f;
        }
    }

    // stable argsort reproduced as rank with original-index tiebreak
    int rnk[24];
#pragma unroll
    for (int k = 0; k < 24; ++k) {
        int r = 0;
#pragma unroll
        for (int j = 0; j < 24; ++j)
            r += (ang[j] < ang[k]) || (ang[j] == ang[k] && j < k);
        rnk[k] = r;
    }

    // shoelace over sorted unmasked points (closed polygon)
    float ssum = 0.f;
#pragma unroll
    for (int k = 0; k < 24; ++k) {
        if ((msk >> k) & 1u) {
            int tgt = (rnk[k] + 1 == cnt) ? 0 : rnk[k] + 1;
            float qx = 0.f, qy = 0.f;
#pragma unroll
            for (int j = 0; j < 24; ++j) {
                if (((msk >> j) & 1u) && rnk[j] == tgt) { qx = rx[j]; qy = ry[j]; }
            }
            ssum += rx[k] * qy - ry[k] * qx;
        }
    }
    float inter = (cnt >= 3) ? 0.5f * fabsf(ssum) : 0.f;
    float uni = ab[2] * ab[3] + gb[2] * gb[3] - inter;
    return inter / fmaxf(uni, 1e-8f);
}

// ---------------------------------------------------------------------------
// Kernel 1: iou matrix [B][A][G]
// ---------------------------------------------------------------------------
__global__ void pair_iou_kernel(const float* __restrict__ anc,
                                const float* __restrict__ ann,
                                float* __restrict__ iou) {
    int tid = blockIdx.x * blockDim.x + threadIdx.x;
    if (tid >= B_ * A_ * G_) return;
    int g = tid & (G_ - 1);
    int a = (tid >> 4) & (A_ - 1);
    int b = tid >> 18;
    const float* ab = anc + ((size_t)b * A_ + a) * 5;
    const float* gb = ann + ((size_t)b * G_ + g) * 6;
    float out;
    if (gb[5] == -1.0f) {
        out = -1.0f;
    } else {
        float sa = 0.5f * fmaxf(ab[2], ab[3]);
        float sb = 0.5f * fmaxf(gb[2], gb[3]);
        float iw = fminf(ab[0] + sa, gb[0] + sb) - fmaxf(ab[0] - sa, gb[0] - sb);
        iw = fmaxf(iw, 0.f);
        float ih = fminf(ab[1] + sa, gb[1] + sb) - fmaxf(ab[1] - sa, gb[1] - sb);
        ih = fmaxf(ih, 0.f);
        float inter = iw * ih;
        float uni = 4.f * sa * sa + 4.f * sb * sb - inter;
        float ind = inter / fmaxf(uni, 1e-8f);
        out = (ind > 0.1f) ? rotated_iou_pair(ab, gb) : 0.f;
    }
    iou[tid] = out;
}

// ---------------------------------------------------------------------------
// Kernel 2: per-anchor max / first-argmax over G; zero forced flags
// ---------------------------------------------------------------------------
__global__ void rowmax_kernel(const float* __restrict__ iou,
                              float* __restrict__ iou_max,
                              int* __restrict__ iou_arg,
                              int* __restrict__ forced) {
    int t = blockIdx.x * blockDim.x + threadIdx.x;
    if (t >= B_ * A_) return;
    const float* row = iou + (size_t)t * G_;
    float m = -2.f; int arg = 0;
#pragma unroll
    for (int g = 0; g < G_; ++g) {
        float v = row[g];
        if (v > m) { m = v; arg = g; }
    }
    iou_max[t] = m;
    iou_arg[t] = arg;
    forced[t] = 0;
}

// ---------------------------------------------------------------------------
// Kernel 3: per-gt max / first-argmax over A; force-match flags
// ---------------------------------------------------------------------------
__global__ void colmax_kernel(const float* __restrict__ iou,
                              const float* __restrict__ ann,
                              int* __restrict__ forced) {
    int b = blockIdx.x / G_;
    int g = blockIdx.x - b * G_;
    __shared__ float sv[256];
    __shared__ int si[256];
    float m = -2.f; int arg = A_;
    for (int a = threadIdx.x; a < A_; a += 256) {
        float v = iou[((size_t)b * A_ + a) * G_ + g];
        if (v > m) { m = v; arg = a; }   // strict > keeps first index per thread
    }
    sv[threadIdx.x] = m; si[threadIdx.x] = arg;
    __syncthreads();
    for (int s = 128; s > 0; s >>= 1) {
        if (threadIdx.x < s) {
            float v2 = sv[threadIdx.x + s]; int i2 = si[threadIdx.x + s];
            if (v2 > sv[threadIdx.x] || (v2 == sv[threadIdx.x] && i2 < si[threadIdx.x])) {
                sv[threadIdx.x] = v2; si[threadIdx.x] = i2;
            }
        }
        __syncthreads();
    }
    if (threadIdx.x == 0) {
        float lab = ann[((size_t)b * G_ + g) * 6 + 5];
        if (lab != -1.0f && sv[0] < 0.5f) forced[b * A_ + si[0]] = 1;
    }
}

// ---------------------------------------------------------------------------
// Kernel 4: per-anchor focal + smooth-L1 contributions, per-block partials
// ---------------------------------------------------------------------------
__global__ void loss_kernel(const float* __restrict__ cls_p,
                            const float* __restrict__ reg_p,
                            const float* __restrict__ anc,
                            const float* __restrict__ ann,
                            const float* __restrict__ iou_max,
                            const int* __restrict__ iou_arg,
                            const int* __restrict__ forced,
                            float* __restrict__ pcls,
                            float* __restrict__ preg,
                            int* __restrict__ pnp) {
    int t = blockIdx.x * blockDim.x + threadIdx.x;  // over B_*A_
    float im = iou_max[t];
    int arg = iou_arg[t];
    int b = t >> 14;
    bool pos = (im >= 0.5f) || (forced[t] != 0);
    const float* g6 = ann + ((size_t)b * G_ + arg) * 6;
    int cls = (int)g6[5];

    float csum = 0.f;
    if (pos || im < 0.4f) {
        const float* pr = cls_p + (size_t)t * C_;
#pragma unroll
        for (int c = 0; c < C_; ++c) {
            float tgt = (pos && c == cls) ? 1.f : 0.f;
            float p = fminf(fmaxf(pr[c], 1e-4f), 1.f - 1e-4f);
            float af = (tgt == 1.f) ? 0.25f : 0.75f;
            float x = (tgt == 1.f) ? (1.f - p) : p;
            float fw = af * x * x;
            float bce = -(tgt * logf(p + 1e-6f) + (1.f - tgt) * logf(1.f - p + 1e-6f));
            csum += fw * bce;
        }
    }

    float rsum = 0.f;
    if (pos) {
        const float* ex = anc + (size_t)t * 5;
        const float* rp = reg_p + (size_t)t * 5;
        float ew = fmaxf(ex[2], 1.f), eh = fmaxf(ex[3], 1.f);
        float gw = fmaxf(g6[2], 1.f), gh = fmaxf(g6[3], 1.f);
        float tg[5];
        tg[0] = 10.f * (g6[0] - ex[0]) / ew;
        tg[1] = 10.f * (g6[1] - ex[1]) / eh;
        tg[2] = 10.f * logf(gw / ew);
        tg[3] = 5.f * logf(gh / eh);
        tg[4] = 15.f * (tanf(g6[4] * D2Rf) - tanf(ex[4] * D2Rf));
        const float BETAf = (float)(1.0 / 9.0);
#pragma unroll
        for (int i = 0; i < 5; ++i) {
            float d = fabsf(rp[i] - tg[i]);
            rsum += (d < BETAf) ? 0.5f * d * d / BETAf : d - 0.5f * BETAf;
        }
    }

    __shared__ float sc[256], sr[256];
    __shared__ int sp[256];
    sc[threadIdx.x] = csum; sr[threadIdx.x] = rsum; sp[threadIdx.x] = pos ? 1 : 0;
    __syncthreads();
    for (int s = 128; s > 0; s >>= 1) {
        if (threadIdx.x < s) {
            sc[threadIdx.x] += sc[threadIdx.x + s];
            sr[threadIdx.x] += sr[threadIdx.x + s];
            sp[threadIdx.x] += sp[threadIdx.x + s];
        }
        __syncthreads();
    }
    if (threadIdx.x == 0) {
        pcls[blockIdx.x] = sc[0];
        preg[blockIdx.x] = sr[0];
        pnp[blockIdx.x] = sp[0];
    }
}

// ---------------------------------------------------------------------------
// Kernel 5: final combine (deterministic ordered sum)
// ---------------------------------------------------------------------------
__global__ void final_kernel(const float* __restrict__ ann,
                             const float* __restrict__ pcls,
                             const float* __restrict__ preg,
                             const int* __restrict__ pnp,
                             float* __restrict__ out) {
    if (threadIdx.x == 0 && blockIdx.x == 0) {
        const int BPI = (B_ * A_ / 256) / B_;  // blocks per image = 64
        float cl[B_], rl[B_];
        for (int b = 0; b < B_; ++b) {
            float cs = 0.f, rs = 0.f; int np = 0;
            for (int i = 0; i < BPI; ++i) {
                cs += pcls[b * BPI + i];
                rs += preg[b * BPI + i];
                np += pnp[b * BPI + i];
            }
            bool has = false;
            for (int g = 0; g < G_; ++g)
                if (ann[((size_t)b * G_ + g) * 6 + 5] != -1.0f) has = true;
            float c_ = cs / fmaxf((float)np, 1.f);
            int d5 = np * 5; if (d5 < 1) d5 = 1;
            float r_ = (np > 0) ? rs / (float)d5 : 0.f;
            cl[b] = has ? c_ : 0.f;
            rl[b] = has ? r_ : 0.f;
        }
        float cm = 0.f, rm = 0.f;
        for (int b = 0; b < B_; ++b) { cm += cl[b]; rm += rl[b]; }
        out[0] = cm / (float)B_;
        out[1] = rm / (float)B_;
    }
}

// ---------------------------------------------------------------------------
extern "C" void kernel_launch(void* const* d_in, const int* in_sizes, int n_in,
                              void* d_out, int out_size, void* d_ws, size_t ws_size,
                              hipStream_t stream) {
    const float* cls_p = (const float*)d_in[0];   // (B,A,C)
    const float* reg_p = (const float*)d_in[1];   // (B,A,5)
    const float* anc   = (const float*)d_in[2];   // (B,A,5)
    const float* ann   = (const float*)d_in[3];   // (B,G,6)
    float* out = (float*)d_out;

    // workspace layout
    float* iou     = (float*)d_ws;                 // B*A*G floats   (2 MB)
    float* iou_max = iou + (size_t)B_ * A_ * G_;   // B*A floats
    int*   iou_arg = (int*)(iou_max + B_ * A_);    // B*A ints
    int*   forced  = iou_arg + B_ * A_;            // B*A ints
    float* pcls    = (float*)(forced + B_ * A_);   // 128 floats
    float* preg    = pcls + 128;                   // 128 floats
    int*   pnp     = (int*)(preg + 128);           // 128 ints

    const int NPAIR = B_ * A_ * G_;
    pair_iou_kernel<<<NPAIR / 256, 256, 0, stream>>>(anc, ann, iou);
    rowmax_kernel<<<(B_ * A_) / 256, 256, 0, stream>>>(iou, iou_max, iou_arg, forced);
    colmax_kernel<<<B_ * G_, 256, 0, stream>>>(iou, ann, forced);
    loss_kernel<<<(B_ * A_) / 256, 256, 0, stream>>>(cls_p, reg_p, anc, ann,
                                                     iou_max, iou_arg, forced,
                                                     pcls, preg, pnp);
    final_kernel<<<1, 64, 0, stream>>>(ann, pcls, preg, pnp, out);
}

// Round 2
// 97.131 us; speedup vs baseline: 1.0632x; 1.0632x over previous
//
#include <hip/hip_runtime.h>

#define B_ 2
#define A_ 16384
#define C_ 15
#define G_ 16
#define D2Rf 0.017453292519943295f
#define ENC_HALF 0xBF000000u  // ordered-uint encoding of 0.5f

__device__ __forceinline__ unsigned enc_f32(float f) {
    unsigned u = __float_as_uint(f);
    return u ^ ((u >> 31) ? 0xFFFFFFFFu : 0x80000000u);
}

// ---------------------------------------------------------------------------
// Rotated IoU, replicating the JAX reference op-for-op in fp32. (unchanged
// from R1 — verified absmax 0.0)
// ---------------------------------------------------------------------------
__device__ __forceinline__ void rect_corners5(const float* b, float X[4], float Y[4],
                                              float* cth, float* sth) {
    float th = b[4] * D2Rf;
    float c = cosf(th), s = sinf(th);
    *cth = c; *sth = s;
    const float SX[4] = {-1.f, 1.f, 1.f, -1.f};
    const float SY[4] = {-1.f, -1.f, 1.f, 1.f};
    float hw = 0.5f * b[2], hh = 0.5f * b[3];
#pragma unroll
    for (int i = 0; i < 4; ++i) {
        float dx = hw * SX[i];
        float dy = hh * SY[i];
        X[i] = b[0] + dx * c - dy * s;
        Y[i] = b[1] + dx * s + dy * c;
    }
}

__device__ float rotated_iou_pair(const float* ab, const float* gb) {
    float ax[4], ay[4], gx[4], gy[4];
    float cA, sA, cG, sG;
    rect_corners5(ab, ax, ay, &cA, &sA);
    rect_corners5(gb, gx, gy, &cG, &sG);

    float rx[24], ry[24];
    unsigned msk = 0u;

#pragma unroll
    for (int i = 0; i < 4; ++i) {
        float dx = ax[i] - gb[0], dy = ay[i] - gb[1];
        float lx = dx * cG + dy * sG;
        float ly = -dx * sG + dy * cG;
        bool in = (fabsf(lx) <= 0.5f * gb[2] + 1e-4f) && (fabsf(ly) <= 0.5f * gb[3] + 1e-4f);
        rx[i] = ax[i]; ry[i] = ay[i];
        if (in) msk |= (1u << i);
    }
#pragma unroll
    for (int i = 0; i < 4; ++i) {
        float dx = gx[i] - ab[0], dy = gy[i] - ab[1];
        float lx = dx * cA + dy * sA;
        float ly = -dx * sA + dy * cA;
        bool in = (fabsf(lx) <= 0.5f * ab[2] + 1e-4f) && (fabsf(ly) <= 0.5f * ab[3] + 1e-4f);
        rx[4 + i] = gx[i]; ry[4 + i] = gy[i];
        if (in) msk |= (1u << (4 + i));
    }
#pragma unroll
    for (int i = 0; i < 4; ++i) {
        float p0x = ax[i], p0y = ay[i];
        float p1x = ax[(i + 1) & 3], p1y = ay[(i + 1) & 3];
        float d1x = p1x - p0x, d1y = p1y - p0y;
#pragma unroll
        for (int j = 0; j < 4; ++j) {
            float q0x = gx[j], q0y = gy[j];
            float q1x = gx[(j + 1) & 3], q1y = gy[(j + 1) & 3];
            float d2x = q1x - q0x, d2y = q1y - q0y;
            float rrx = q0x - p0x, rry = q0y - p0y;
            float den = d1x * d2y - d1y * d2x;
            float safe = (fabsf(den) < 1e-8f) ? 1.f : den;
            float t = (rrx * d2y - rry * d2x) / safe;
            float u = (rrx * d1y - rry * d1x) / safe;
            bool ok = (fabsf(den) >= 1e-8f) && (t >= 0.f) && (t <= 1.f) && (u >= 0.f) && (u <= 1.f);
            int k = 8 + i * 4 + j;
            rx[k] = p0x + t * d1x;
            ry[k] = p0y + t * d1y;
            if (ok) msk |= (1u << k);
        }
    }

    int cnt = __popc(msk);
    float sx = 0.f, sy = 0.f;
#pragma unroll
    for (int k = 0; k < 24; ++k)
        if ((msk >> k) & 1u) { sx += rx[k]; sy += ry[k]; }
    float cnf = fmaxf((float)cnt, 1.f);
    float cenx = sx / cnf, ceny = sy / cnf;

    float ang[24];
#pragma unroll
    for (int k = 0; k < 24; ++k) {
        if ((msk >> k) & 1u) {
            rx[k] -= cenx; ry[k] -= ceny;
            ang[k] = atan2f(ry[k], rx[k]);
        } else {
            rx[k] = 0.f; ry[k] = 0.f;
            ang[k] = 1e9f;
        }
    }

    int rnk[24];
#pragma unroll
    for (int k = 0; k < 24; ++k) {
        int r = 0;
#pragma unroll
        for (int j = 0; j < 24; ++j)
            r += (ang[j] < ang[k]) || (ang[j] == ang[k] && j < k);
        rnk[k] = r;
    }

    float ssum = 0.f;
#pragma unroll
    for (int k = 0; k < 24; ++k) {
        if ((msk >> k) & 1u) {
            int tgt = (rnk[k] + 1 == cnt) ? 0 : rnk[k] + 1;
            float qx = 0.f, qy = 0.f;
#pragma unroll
            for (int j = 0; j < 24; ++j) {
                if (((msk >> j) & 1u) && rnk[j] == tgt) { qx = rx[j]; qy = ry[j]; }
            }
            ssum += rx[k] * qy - ry[k] * qx;
        }
    }
    float inter = (cnt >= 3) ? 0.5f * fabsf(ssum) : 0.f;
    float uni = ab[2] * ab[3] + gb[2] * gb[3] - inter;
    return inter / fmaxf(uni, 1e-8f);
}

// ---------------------------------------------------------------------------
// Kernel 1: gate — light iou values + compacted worklist of heavy pairs.
// One thread per anchor (16 gts each); block-aggregated append (1 atomic/blk).
// ---------------------------------------------------------------------------
__global__ void gate_kernel(const float* __restrict__ anc,
                            const float* __restrict__ ann,
                            float* __restrict__ iou,
                            unsigned* __restrict__ counter,
                            unsigned* __restrict__ wl) {
    int t = blockIdx.x * blockDim.x + threadIdx.x;   // anchor id in [0, B*A)
    int b = t >> 14;
    const float* ab = anc + (size_t)t * 5;
    float a0 = ab[0], a1 = ab[1], a2 = ab[2], a3 = ab[3];
    float sa = 0.5f * fmaxf(a2, a3);

    unsigned passmask = 0u;
    float vals[16];
#pragma unroll
    for (int g = 0; g < 16; ++g) {
        const float* gb = ann + ((size_t)b * G_ + g) * 6;
        float lab = gb[5];
        float v;
        if (lab == -1.0f) {
            v = -1.0f;
        } else {
            float sb = 0.5f * fmaxf(gb[2], gb[3]);
            float iw = fminf(a0 + sa, gb[0] + sb) - fmaxf(a0 - sa, gb[0] - sb);
            iw = fmaxf(iw, 0.f);
            float ih = fminf(a1 + sa, gb[1] + sb) - fmaxf(a1 - sa, gb[1] - sb);
            ih = fmaxf(ih, 0.f);
            float inter = iw * ih;
            float uni = 4.f * sa * sa + 4.f * sb * sb - inter;
            float ind = inter / fmaxf(uni, 1e-8f);
            if (ind > 0.1f) passmask |= (1u << g);
            v = 0.f;   // overwritten by heavy kernel for passing pairs
        }
        vals[g] = v;
    }
    // coalesced 64B store of the light values
    float4* o4 = (float4*)(iou + (size_t)t * 16);
#pragma unroll
    for (int q = 0; q < 4; ++q)
        o4[q] = make_float4(vals[q * 4], vals[q * 4 + 1], vals[q * 4 + 2], vals[q * 4 + 3]);

    // block-wide compaction
    int cnt = __popc(passmask);
    __shared__ int ss[256];
    __shared__ unsigned sbase;
    ss[threadIdx.x] = cnt;
    __syncthreads();
    for (int s = 1; s < 256; s <<= 1) {
        int v = (threadIdx.x >= s) ? ss[threadIdx.x - s] : 0;
        __syncthreads();
        ss[threadIdx.x] += v;
        __syncthreads();
    }
    if (threadIdx.x == 0) sbase = atomicAdd(counter, (unsigned)ss[255]);
    __syncthreads();
    unsigned pos = sbase + (unsigned)(ss[threadIdx.x] - cnt);
    unsigned base_pid = (unsigned)t * 16u;
#pragma unroll
    for (int g = 0; g < 16; ++g) {
        if ((passmask >> g) & 1u) wl[pos++] = base_pid + g;
    }
}

// ---------------------------------------------------------------------------
// Kernel 2: heavy — dense rotated IoU over the worklist (grid-stride).
// ---------------------------------------------------------------------------
__global__ void heavy_kernel(const float* __restrict__ anc,
                             const float* __restrict__ ann,
                             const unsigned* __restrict__ wl,
                             const unsigned* __restrict__ counter,
                             float* __restrict__ iou) {
    unsigned n = *counter;
    for (unsigned i = blockIdx.x * blockDim.x + threadIdx.x; i < n;
         i += gridDim.x * blockDim.x) {
        unsigned pid = wl[i];
        int g = pid & 15;
        int a = (pid >> 4) & (A_ - 1);
        int b = pid >> 18;
        const float* ab = anc + ((size_t)b * A_ + a) * 5;
        const float* gb = ann + ((size_t)b * G_ + g) * 6;
        iou[pid] = rotated_iou_pair(ab, gb);
    }
}

// ---------------------------------------------------------------------------
// Kernel 3: column max/argmax via packed-u64 atomicMax (deterministic:
// value-desc, index-asc tiebreak encoded in one monotone key).
// ---------------------------------------------------------------------------
__global__ void colmax_kernel(const float* __restrict__ iou,
                              unsigned long long* __restrict__ packed) {
    int t = blockIdx.x * blockDim.x + threadIdx.x;  // anchor id
    int b = t >> 14;
    int a = t & (A_ - 1);
    const float4* r4 = (const float4*)(iou + (size_t)t * 16);
    float rowv[16];
#pragma unroll
    for (int q = 0; q < 4; ++q) {
        float4 v = r4[q];
        rowv[q * 4] = v.x; rowv[q * 4 + 1] = v.y; rowv[q * 4 + 2] = v.z; rowv[q * 4 + 3] = v.w;
    }
    unsigned long long pk[16];
#pragma unroll
    for (int g = 0; g < 16; ++g)
        pk[g] = ((unsigned long long)enc_f32(rowv[g]) << 32) | (0xFFFFFFFFu - (unsigned)a);
    // wave butterfly reduce (max) per g
#pragma unroll
    for (int g = 0; g < 16; ++g) {
#pragma unroll
        for (int off = 1; off < 64; off <<= 1) {
            unsigned long long o = __shfl_xor(pk[g], off);
            if (o > pk[g]) pk[g] = o;
        }
    }
    if ((threadIdx.x & 63) == 0) {
#pragma unroll
        for (int g = 0; g < 16; ++g)
            atomicMax(&packed[b * G_ + g], pk[g]);
    }
}

// ---------------------------------------------------------------------------
// Kernel 4: per-anchor loss (rowmax + forced check inline), block partials.
// ---------------------------------------------------------------------------
__global__ void loss_kernel(const float* __restrict__ cls_p,
                            const float* __restrict__ reg_p,
                            const float* __restrict__ anc,
                            const float* __restrict__ ann,
                            const float* __restrict__ iou,
                            const unsigned long long* __restrict__ packed,
                            float* __restrict__ pcls,
                            float* __restrict__ preg,
                            int* __restrict__ pnp) {
    int t = blockIdx.x * blockDim.x + threadIdx.x;  // over B_*A_
    int b = t >> 14;
    int a = t & (A_ - 1);

    // row max / first-argmax over G
    const float4* r4 = (const float4*)(iou + (size_t)t * 16);
    float im = -2.f; int arg = 0;
#pragma unroll
    for (int q = 0; q < 4; ++q) {
        float4 v = r4[q];
        float vv[4] = {v.x, v.y, v.z, v.w};
#pragma unroll
        for (int j = 0; j < 4; ++j) {
            if (vv[j] > im) { im = vv[j]; arg = q * 4 + j; }
        }
    }

    // forced flag: some gt's column-argmax is this anchor, with colmax < 0.5
    bool forcedf = false;
#pragma unroll
    for (int g = 0; g < 16; ++g) {
        unsigned long long pk = packed[b * G_ + g];     // uniform -> scalar
        float lab = ann[((size_t)b * G_ + g) * 6 + 5];  // uniform -> scalar
        unsigned hi = (unsigned)(pk >> 32);
        unsigned ai = 0xFFFFFFFFu - (unsigned)pk;
        forcedf |= (lab != -1.0f) && (hi < ENC_HALF) && (ai == (unsigned)a);
    }

    bool pos = (im >= 0.5f) || forcedf;
    const float* g6 = ann + ((size_t)b * G_ + arg) * 6;
    int cls = (int)g6[5];

    float csum = 0.f;
    if (pos || im < 0.4f) {
        const float* pr = cls_p + (size_t)t * C_;
#pragma unroll
        for (int c = 0; c < C_; ++c) {
            float tgt = (pos && c == cls) ? 1.f : 0.f;
            float p = fminf(fmaxf(pr[c], 1e-4f), 1.f - 1e-4f);
            float af = (tgt == 1.f) ? 0.25f : 0.75f;
            float x = (tgt == 1.f) ? (1.f - p) : p;
            float fw = af * x * x;
            float bce = -(tgt * logf(p + 1e-6f) + (1.f - tgt) * logf(1.f - p + 1e-6f));
            csum += fw * bce;
        }
    }

    float rsum = 0.f;
    if (pos) {
        const float* ex = anc + (size_t)t * 5;
        const float* rp = reg_p + (size_t)t * 5;
        float ew = fmaxf(ex[2], 1.f), eh = fmaxf(ex[3], 1.f);
        float gw = fmaxf(g6[2], 1.f), gh = fmaxf(g6[3], 1.f);
        float tg[5];
        tg[0] = 10.f * (g6[0] - ex[0]) / ew;
        tg[1] = 10.f * (g6[1] - ex[1]) / eh;
        tg[2] = 10.f * logf(gw / ew);
        tg[3] = 5.f * logf(gh / eh);
        tg[4] = 15.f * (tanf(g6[4] * D2Rf) - tanf(ex[4] * D2Rf));
        const float BETAf = (float)(1.0 / 9.0);
#pragma unroll
        for (int i = 0; i < 5; ++i) {
            float d = fabsf(rp[i] - tg[i]);
            rsum += (d < BETAf) ? 0.5f * d * d / BETAf : d - 0.5f * BETAf;
        }
    }

    __shared__ float sc[256], sr[256];
    __shared__ int sp[256];
    sc[threadIdx.x] = csum; sr[threadIdx.x] = rsum; sp[threadIdx.x] = pos ? 1 : 0;
    __syncthreads();
    for (int s = 128; s > 0; s >>= 1) {
        if (threadIdx.x < s) {
            sc[threadIdx.x] += sc[threadIdx.x + s];
            sr[threadIdx.x] += sr[threadIdx.x + s];
            sp[threadIdx.x] += sp[threadIdx.x + s];
        }
        __syncthreads();
    }
    if (threadIdx.x == 0) {
        pcls[blockIdx.x] = sc[0];
        preg[blockIdx.x] = sr[0];
        pnp[blockIdx.x] = sp[0];
    }
}

// ---------------------------------------------------------------------------
// Kernel 5: final combine (deterministic ordered sum)
// ---------------------------------------------------------------------------
__global__ void final_kernel(const float* __restrict__ ann,
                             const float* __restrict__ pcls,
                             const float* __restrict__ preg,
                             const int* __restrict__ pnp,
                             float* __restrict__ out) {
    if (threadIdx.x == 0 && blockIdx.x == 0) {
        const int BPI = (B_ * A_ / 256) / B_;  // blocks per image = 64
        float cl[B_], rl[B_];
        for (int b = 0; b < B_; ++b) {
            float cs = 0.f, rs = 0.f; int np = 0;
            for (int i = 0; i < BPI; ++i) {
                cs += pcls[b * BPI + i];
                rs += preg[b * BPI + i];
                np += pnp[b * BPI + i];
            }
            bool has = false;
            for (int g = 0; g < G_; ++g)
                if (ann[((size_t)b * G_ + g) * 6 + 5] != -1.0f) has = true;
            float c_ = cs / fmaxf((float)np, 1.f);
            int d5 = np * 5; if (d5 < 1) d5 = 1;
            float r_ = (np > 0) ? rs / (float)d5 : 0.f;
            cl[b] = has ? c_ : 0.f;
            rl[b] = has ? r_ : 0.f;
        }
        float cm = 0.f, rm = 0.f;
        for (int b = 0; b < B_; ++b) { cm += cl[b]; rm += rl[b]; }
        out[0] = cm / (float)B_;
        out[1] = rm / (float)B_;
    }
}

// ---------------------------------------------------------------------------
extern "C" void kernel_launch(void* const* d_in, const int* in_sizes, int n_in,
                              void* d_out, int out_size, void* d_ws, size_t ws_size,
                              hipStream_t stream) {
    const float* cls_p = (const float*)d_in[0];   // (B,A,C)
    const float* reg_p = (const float*)d_in[1];   // (B,A,5)
    const float* anc   = (const float*)d_in[2];   // (B,A,5)
    const float* ann   = (const float*)d_in[3];   // (B,G,6)
    float* out = (float*)d_out;

    // workspace layout
    char* ws = (char*)d_ws;
    unsigned* counter = (unsigned*)ws;                       // offset 0, 4B
    unsigned long long* packed = (unsigned long long*)(ws + 256);  // 32 * 8B
    float* iou = (float*)(ws + 512);                         // B*A*G floats (2 MB)
    float* pcls = iou + (size_t)B_ * A_ * G_;                // 128 floats
    float* preg = pcls + 128;
    int*   pnp  = (int*)(preg + 128);
    unsigned* wl = (unsigned*)(pnp + 128);                   // up to B*A*G u32 (2 MB)

    // zero counter + packed cells (512 B)
    hipMemsetAsync(ws, 0, 512, stream);

    gate_kernel<<<(B_ * A_) / 256, 256, 0, stream>>>(anc, ann, iou, counter, wl);
    heavy_kernel<<<256, 256, 0, stream>>>(anc, ann, wl, counter, iou);
    colmax_kernel<<<(B_ * A_) / 256, 256, 0, stream>>>(iou, packed);
    loss_kernel<<<(B_ * A_) / 256, 256, 0, stream>>>(cls_p, reg_p, anc, ann, iou,
                                                     packed, pcls, preg, pnp);
    final_kernel<<<1, 64, 0, stream>>>(ann, pcls, preg, pnp, out);
}

// Round 3
// 56.962 us; speedup vs baseline: 1.8130x; 1.7052x over previous
//
#include <hip/hip_runtime.h>

#define B_ 2
#define A_ 16384
#define C_ 15
#define G_ 16
#define D2Rf 0.017453292519943295f
#define ENC_HALF 0xBF000000u  // ordered-uint encoding of 0.5f
#define HB_ 128               // heavy-kernel blocks

__device__ __forceinline__ unsigned enc_f32(float f) {
    unsigned u = __float_as_uint(f);
    return u ^ ((u >> 31) ? 0xFFFFFFFFu : 0x80000000u);
}

// ---------------------------------------------------------------------------
// Rotated IoU, replicating the JAX reference op-for-op in fp32.
// (verified absmax 0.0 in R1/R2)
// ---------------------------------------------------------------------------
__device__ __forceinline__ void rect_corners5(const float* b, float X[4], float Y[4],
                                              float* cth, float* sth) {
    float th = b[4] * D2Rf;
    float c = cosf(th), s = sinf(th);
    *cth = c; *sth = s;
    const float SX[4] = {-1.f, 1.f, 1.f, -1.f};
    const float SY[4] = {-1.f, -1.f, 1.f, 1.f};
    float hw = 0.5f * b[2], hh = 0.5f * b[3];
#pragma unroll
    for (int i = 0; i < 4; ++i) {
        float dx = hw * SX[i];
        float dy = hh * SY[i];
        X[i] = b[0] + dx * c - dy * s;
        Y[i] = b[1] + dx * s + dy * c;
    }
}

__device__ float rotated_iou_pair(const float* ab, const float* gb) {
    float ax[4], ay[4], gx[4], gy[4];
    float cA, sA, cG, sG;
    rect_corners5(ab, ax, ay, &cA, &sA);
    rect_corners5(gb, gx, gy, &cG, &sG);

    float rx[24], ry[24];
    unsigned msk = 0u;

#pragma unroll
    for (int i = 0; i < 4; ++i) {
        float dx = ax[i] - gb[0], dy = ay[i] - gb[1];
        float lx = dx * cG + dy * sG;
        float ly = -dx * sG + dy * cG;
        bool in = (fabsf(lx) <= 0.5f * gb[2] + 1e-4f) && (fabsf(ly) <= 0.5f * gb[3] + 1e-4f);
        rx[i] = ax[i]; ry[i] = ay[i];
        if (in) msk |= (1u << i);
    }
#pragma unroll
    for (int i = 0; i < 4; ++i) {
        float dx = gx[i] - ab[0], dy = gy[i] - ab[1];
        float lx = dx * cA + dy * sA;
        float ly = -dx * sA + dy * cA;
        bool in = (fabsf(lx) <= 0.5f * ab[2] + 1e-4f) && (fabsf(ly) <= 0.5f * ab[3] + 1e-4f);
        rx[4 + i] = gx[i]; ry[4 + i] = gy[i];
        if (in) msk |= (1u << (4 + i));
    }
#pragma unroll
    for (int i = 0; i < 4; ++i) {
        float p0x = ax[i], p0y = ay[i];
        float p1x = ax[(i + 1) & 3], p1y = ay[(i + 1) & 3];
        float d1x = p1x - p0x, d1y = p1y - p0y;
#pragma unroll
        for (int j = 0; j < 4; ++j) {
            float q0x = gx[j], q0y = gy[j];
            float q1x = gx[(j + 1) & 3], q1y = gy[(j + 1) & 3];
            float d2x = q1x - q0x, d2y = q1y - q0y;
            float rrx = q0x - p0x, rry = q0y - p0y;
            float den = d1x * d2y - d1y * d2x;
            float safe = (fabsf(den) < 1e-8f) ? 1.f : den;
            float t = (rrx * d2y - rry * d2x) / safe;
            float u = (rrx * d1y - rry * d1x) / safe;
            bool ok = (fabsf(den) >= 1e-8f) && (t >= 0.f) && (t <= 1.f) && (u >= 0.f) && (u <= 1.f);
            int k = 8 + i * 4 + j;
            rx[k] = p0x + t * d1x;
            ry[k] = p0y + t * d1y;
            if (ok) msk |= (1u << k);
        }
    }

    int cnt = __popc(msk);
    float sx = 0.f, sy = 0.f;
#pragma unroll
    for (int k = 0; k < 24; ++k)
        if ((msk >> k) & 1u) { sx += rx[k]; sy += ry[k]; }
    float cnf = fmaxf((float)cnt, 1.f);
    float cenx = sx / cnf, ceny = sy / cnf;

    float ang[24];
#pragma unroll
    for (int k = 0; k < 24; ++k) {
        if ((msk >> k) & 1u) {
            rx[k] -= cenx; ry[k] -= ceny;
            ang[k] = atan2f(ry[k], rx[k]);
        } else {
            rx[k] = 0.f; ry[k] = 0.f;
            ang[k] = 1e9f;
        }
    }

    int rnk[24];
#pragma unroll
    for (int k = 0; k < 24; ++k) {
        int r = 0;
#pragma unroll
        for (int j = 0; j < 24; ++j)
            r += (ang[j] < ang[k]) || (ang[j] == ang[k] && j < k);
        rnk[k] = r;
    }

    float ssum = 0.f;
#pragma unroll
    for (int k = 0; k < 24; ++k) {
        if ((msk >> k) & 1u) {
            int tgt = (rnk[k] + 1 == cnt) ? 0 : rnk[k] + 1;
            float qx = 0.f, qy = 0.f;
#pragma unroll
            for (int j = 0; j < 24; ++j) {
                if (((msk >> j) & 1u) && rnk[j] == tgt) { qx = rx[j]; qy = ry[j]; }
            }
            ssum += rx[k] * qy - ry[k] * qx;
        }
    }
    float inter = (cnt >= 3) ? 0.5f * fabsf(ssum) : 0.f;
    float uni = ab[2] * ab[3] + gb[2] * gb[3] - inter;
    return inter / fmaxf(uni, 1e-8f);
}

// ---------------------------------------------------------------------------
// Kernel 1: gate — light iou values + compacted worklist of heavy pairs.
// ---------------------------------------------------------------------------
__global__ void gate_kernel(const float* __restrict__ anc,
                            const float* __restrict__ ann,
                            float* __restrict__ iou,
                            unsigned* __restrict__ counter,
                            unsigned* __restrict__ wl) {
    int t = blockIdx.x * blockDim.x + threadIdx.x;   // anchor id in [0, B*A)
    int b = t >> 14;
    const float* ab = anc + (size_t)t * 5;
    float a0 = ab[0], a1 = ab[1], a2 = ab[2], a3 = ab[3];
    float sa = 0.5f * fmaxf(a2, a3);

    unsigned passmask = 0u;
    float vals[16];
#pragma unroll
    for (int g = 0; g < 16; ++g) {
        const float* gb = ann + ((size_t)b * G_ + g) * 6;
        float lab = gb[5];
        float v;
        if (lab == -1.0f) {
            v = -1.0f;
        } else {
            float sb = 0.5f * fmaxf(gb[2], gb[3]);
            float iw = fminf(a0 + sa, gb[0] + sb) - fmaxf(a0 - sa, gb[0] - sb);
            iw = fmaxf(iw, 0.f);
            float ih = fminf(a1 + sa, gb[1] + sb) - fmaxf(a1 - sa, gb[1] - sb);
            ih = fmaxf(ih, 0.f);
            float inter = iw * ih;
            float uni = 4.f * sa * sa + 4.f * sb * sb - inter;
            float ind = inter / fmaxf(uni, 1e-8f);
            if (ind > 0.1f) passmask |= (1u << g);
            v = 0.f;   // overwritten by heavy kernel for passing pairs
        }
        vals[g] = v;
    }
    float4* o4 = (float4*)(iou + (size_t)t * 16);
#pragma unroll
    for (int q = 0; q < 4; ++q)
        o4[q] = make_float4(vals[q * 4], vals[q * 4 + 1], vals[q * 4 + 2], vals[q * 4 + 3]);

    // block-wide compaction
    int cnt = __popc(passmask);
    __shared__ int ss[256];
    __shared__ unsigned sbase;
    ss[threadIdx.x] = cnt;
    __syncthreads();
    for (int s = 1; s < 256; s <<= 1) {
        int v = (threadIdx.x >= s) ? ss[threadIdx.x - s] : 0;
        __syncthreads();
        ss[threadIdx.x] += v;
        __syncthreads();
    }
    if (threadIdx.x == 0) sbase = atomicAdd(counter, (unsigned)ss[255]);
    __syncthreads();
    unsigned pos = sbase + (unsigned)(ss[threadIdx.x] - cnt);
    unsigned base_pid = (unsigned)t * 16u;
#pragma unroll
    for (int g = 0; g < 16; ++g) {
        if ((passmask >> g) & 1u) wl[pos++] = base_pid + g;
    }
}

// ---------------------------------------------------------------------------
// Kernel 2: heavy — dense rotated IoU over the worklist; per-block colmax
// partials via LDS atomicMax (block-scope, deterministic: max is assoc/comm).
// ---------------------------------------------------------------------------
__global__ void heavy_kernel(const float* __restrict__ anc,
                             const float* __restrict__ ann,
                             const unsigned* __restrict__ wl,
                             const unsigned* __restrict__ counter,
                             float* __restrict__ iou,
                             unsigned long long* __restrict__ partials) {
    __shared__ unsigned long long cells[32];
    if (threadIdx.x < 32) cells[threadIdx.x] = 0ull;  // 0 < any real key
    __syncthreads();
    unsigned n = *counter;
    for (unsigned i = blockIdx.x * blockDim.x + threadIdx.x; i < n;
         i += gridDim.x * blockDim.x) {
        unsigned pid = wl[i];
        int g = pid & 15;
        int a = (pid >> 4) & (A_ - 1);
        int b = pid >> 18;
        const float* ab = anc + ((size_t)b * A_ + a) * 5;
        const float* gb = ann + ((size_t)b * G_ + g) * 6;
        float v = rotated_iou_pair(ab, gb);
        iou[pid] = v;
        unsigned long long key =
            ((unsigned long long)enc_f32(v) << 32) | (0xFFFFFFFFu - (unsigned)a);
        atomicMax(&cells[b * G_ + g], key);
    }
    __syncthreads();
    if (threadIdx.x < 32)
        partials[(size_t)blockIdx.x * 32 + threadIdx.x] = cells[threadIdx.x];
}

// ---------------------------------------------------------------------------
// Kernel 3: reduce per-block colmax partials + default candidate (0.0, a=0).
// For a valid gt, every non-heavy column entry is exactly 0.0, so the column
// argmax is max(best heavy pair, (0.0, anchor 0)).
// ---------------------------------------------------------------------------
__global__ void colfinal_kernel(const unsigned long long* __restrict__ partials,
                                unsigned long long* __restrict__ packed) {
    __shared__ unsigned long long red[256];
    int cell = threadIdx.x & 31, chunk = threadIdx.x >> 5;  // 8 chunks x 16 blocks
    unsigned long long m = 0ull;
    for (int blk = chunk * (HB_ / 8); blk < (chunk + 1) * (HB_ / 8); ++blk) {
        unsigned long long v = partials[(size_t)blk * 32 + cell];
        if (v > m) m = v;
    }
    red[threadIdx.x] = m;
    __syncthreads();
    if (threadIdx.x < 32) {
        unsigned long long mm =
            ((unsigned long long)enc_f32(0.0f) << 32) | 0xFFFFFFFFu;  // (0.0, a=0)
        for (int c = 0; c < 8; ++c) {
            unsigned long long v = red[c * 32 + threadIdx.x];
            if (v > mm) mm = v;
        }
        packed[threadIdx.x] = mm;
    }
}

// ---------------------------------------------------------------------------
// Kernel 4: per-anchor loss (rowmax + forced check inline), block partials.
// ---------------------------------------------------------------------------
__global__ void loss_kernel(const float* __restrict__ cls_p,
                            const float* __restrict__ reg_p,
                            const float* __restrict__ anc,
                            const float* __restrict__ ann,
                            const float* __restrict__ iou,
                            const unsigned long long* __restrict__ packed,
                            float* __restrict__ pcls,
                            float* __restrict__ preg,
                            int* __restrict__ pnp) {
    int t = blockIdx.x * blockDim.x + threadIdx.x;  // over B_*A_
    int b = t >> 14;
    int a = t & (A_ - 1);

    // row max / first-argmax over G
    const float4* r4 = (const float4*)(iou + (size_t)t * 16);
    float im = -2.f; int arg = 0;
#pragma unroll
    for (int q = 0; q < 4; ++q) {
        float4 v = r4[q];
        float vv[4] = {v.x, v.y, v.z, v.w};
#pragma unroll
        for (int j = 0; j < 4; ++j) {
            if (vv[j] > im) { im = vv[j]; arg = q * 4 + j; }
        }
    }

    // forced flag: some gt's column-argmax is this anchor, with colmax < 0.5
    bool forcedf = false;
#pragma unroll
    for (int g = 0; g < 16; ++g) {
        unsigned long long pk = packed[b * G_ + g];     // uniform -> scalar
        float lab = ann[((size_t)b * G_ + g) * 6 + 5];  // uniform -> scalar
        unsigned hi = (unsigned)(pk >> 32);
        unsigned ai = 0xFFFFFFFFu - (unsigned)pk;
        forcedf |= (lab != -1.0f) && (hi < ENC_HALF) && (ai == (unsigned)a);
    }

    bool pos = (im >= 0.5f) || forcedf;
    const float* g6 = ann + ((size_t)b * G_ + arg) * 6;
    int cls = (int)g6[5];

    float csum = 0.f;
    if (pos || im < 0.4f) {
        const float* pr = cls_p + (size_t)t * C_;
#pragma unroll
        for (int c = 0; c < C_; ++c) {
            float tgt = (pos && c == cls) ? 1.f : 0.f;
            float p = fminf(fmaxf(pr[c], 1e-4f), 1.f - 1e-4f);
            float af = (tgt == 1.f) ? 0.25f : 0.75f;
            float x = (tgt == 1.f) ? (1.f - p) : p;
            float fw = af * x * x;
            float bce = -(tgt * logf(p + 1e-6f) + (1.f - tgt) * logf(1.f - p + 1e-6f));
            csum += fw * bce;
        }
    }

    float rsum = 0.f;
    if (pos) {
        const float* ex = anc + (size_t)t * 5;
        const float* rp = reg_p + (size_t)t * 5;
        float ew = fmaxf(ex[2], 1.f), eh = fmaxf(ex[3], 1.f);
        float gw = fmaxf(g6[2], 1.f), gh = fmaxf(g6[3], 1.f);
        float tg[5];
        tg[0] = 10.f * (g6[0] - ex[0]) / ew;
        tg[1] = 10.f * (g6[1] - ex[1]) / eh;
        tg[2] = 10.f * logf(gw / ew);
        tg[3] = 5.f * logf(gh / eh);
        tg[4] = 15.f * (tanf(g6[4] * D2Rf) - tanf(ex[4] * D2Rf));
        const float BETAf = (float)(1.0 / 9.0);
#pragma unroll
        for (int i = 0; i < 5; ++i) {
            float d = fabsf(rp[i] - tg[i]);
            rsum += (d < BETAf) ? 0.5f * d * d / BETAf : d - 0.5f * BETAf;
        }
    }

    __shared__ float sc[256], sr[256];
    __shared__ int sp[256];
    sc[threadIdx.x] = csum; sr[threadIdx.x] = rsum; sp[threadIdx.x] = pos ? 1 : 0;
    __syncthreads();
    for (int s = 128; s > 0; s >>= 1) {
        if (threadIdx.x < s) {
            sc[threadIdx.x] += sc[threadIdx.x + s];
            sr[threadIdx.x] += sr[threadIdx.x + s];
            sp[threadIdx.x] += sp[threadIdx.x + s];
        }
        __syncthreads();
    }
    if (threadIdx.x == 0) {
        pcls[blockIdx.x] = sc[0];
        preg[blockIdx.x] = sr[0];
        pnp[blockIdx.x] = sp[0];
    }
}

// ---------------------------------------------------------------------------
// Kernel 5: final combine (deterministic ordered sum)
// ---------------------------------------------------------------------------
__global__ void final_kernel(const float* __restrict__ ann,
                             const float* __restrict__ pcls,
                             const float* __restrict__ preg,
                             const int* __restrict__ pnp,
                             float* __restrict__ out) {
    if (threadIdx.x == 0 && blockIdx.x == 0) {
        const int BPI = (B_ * A_ / 256) / B_;  // blocks per image = 64
        float cl[B_], rl[B_];
        for (int b = 0; b < B_; ++b) {
            float cs = 0.f, rs = 0.f; int np = 0;
            for (int i = 0; i < BPI; ++i) {
                cs += pcls[b * BPI + i];
                rs += preg[b * BPI + i];
                np += pnp[b * BPI + i];
            }
            bool has = false;
            for (int g = 0; g < G_; ++g)
                if (ann[((size_t)b * G_ + g) * 6 + 5] != -1.0f) has = true;
            float c_ = cs / fmaxf((float)np, 1.f);
            int d5 = np * 5; if (d5 < 1) d5 = 1;
            float r_ = (np > 0) ? rs / (float)d5 : 0.f;
            cl[b] = has ? c_ : 0.f;
            rl[b] = has ? r_ : 0.f;
        }
        float cm = 0.f, rm = 0.f;
        for (int b = 0; b < B_; ++b) { cm += cl[b]; rm += rl[b]; }
        out[0] = cm / (float)B_;
        out[1] = rm / (float)B_;
    }
}

// ---------------------------------------------------------------------------
extern "C" void kernel_launch(void* const* d_in, const int* in_sizes, int n_in,
                              void* d_out, int out_size, void* d_ws, size_t ws_size,
                              hipStream_t stream) {
    const float* cls_p = (const float*)d_in[0];   // (B,A,C)
    const float* reg_p = (const float*)d_in[1];   // (B,A,5)
    const float* anc   = (const float*)d_in[2];   // (B,A,5)
    const float* ann   = (const float*)d_in[3];   // (B,G,6)
    float* out = (float*)d_out;

    // workspace layout
    char* ws = (char*)d_ws;
    unsigned* counter = (unsigned*)ws;                             // 4B
    unsigned long long* packed = (unsigned long long*)(ws + 256);  // 32 * 8B
    float* iou = (float*)(ws + 512);                               // B*A*G (2 MB)
    float* pcls = iou + (size_t)B_ * A_ * G_;                      // 128
    float* preg = pcls + 128;
    int*   pnp  = (int*)(preg + 128);
    unsigned* wl = (unsigned*)(pnp + 128);                         // B*A*G u32 (2 MB)
    unsigned long long* partials =
        (unsigned long long*)(wl + (size_t)B_ * A_ * G_);          // HB_*32*8 = 32 KB

    hipMemsetAsync(counter, 0, 4, stream);

    gate_kernel<<<(B_ * A_) / 256, 256, 0, stream>>>(anc, ann, iou, counter, wl);
    heavy_kernel<<<HB_, 256, 0, stream>>>(anc, ann, wl, counter, iou, partials);
    colfinal_kernel<<<1, 256, 0, stream>>>(partials, packed);
    loss_kernel<<<(B_ * A_) / 256, 256, 0, stream>>>(cls_p, reg_p, anc, ann, iou,
                                                     packed, pcls, preg, pnp);
    final_kernel<<<1, 64, 0, stream>>>(ann, pcls, preg, pnp, out);
}